// Round 10
// baseline (95.788 us; speedup 1.0000x reference)
//
#include <hip/hip_runtime.h>
#include <hip/hip_bf16.h>
#include <math.h>

#define BSZ   128
#define NP    16
#define NC    21
#define NH    256
#define HOUT  16
#define NFLAT 5376     // K (permuted layout k' = p*336 + c*16 + wo)

typedef __attribute__((ext_vector_type(4))) float f32x4;
typedef __attribute__((ext_vector_type(8))) short bf16x8;

__device__ __forceinline__ ushort f2bf(float v) {
    __hip_bfloat16 h = __float2bfloat16(v);
    return *reinterpret_cast<ushort*>(&h);
}

// tanh(0.01*ln(s)) via odd poly: u in [-0.23, 0.03]; err < 2e-6
__device__ __forceinline__ float hist_act(float s) {
    float u = 0.01f * __logf(fmaxf(s, 1e-10f));
    float u2 = u * u;
    return u * (1.f + u2 * (-0.33333333f + 0.13333333f * u2));
}

// tanh(x) = 1 - 2/(e^{2x}+1)
__device__ __forceinline__ float fast_tanh(float v) {
    float e = __expf(2.f * v);
    return 1.f - 2.f * __builtin_amdgcn_rcpf(e + 1.f);
}

// ---------------------------------------------------------------------------
// Kernel 1: blocks 0..2047 RBF (one (b,p) tile), blocks 2048..2383 W-prep.
// x layout: [2048][5376] bf16, k' = p*336 + c*16 + wo
// ---------------------------------------------------------------------------
__global__ __launch_bounds__(256) void k_pre(const float* __restrict__ sim,
                                             ushort* __restrict__ x,
                                             const float* __restrict__ W,
                                             ushort* __restrict__ Wt) {
    int tid = threadIdx.x;

    if (blockIdx.x >= 2048) {
        __shared__ ushort ldsT[64][72];
        int pb = blockIdx.x - 2048;          // 0..335
        int kb = pb % 84, nb = pb / 84;
        int k0 = kb * 64, n0 = nb * 64;
        int nl = tid & 63, kq = tid >> 6;
#pragma unroll
        for (int i = 0; i < 16; ++i) {
            int kl = i * 4 + kq;
            ldsT[nl][kl] = f2bf(W[(size_t)(k0 + kl) * NH + n0 + nl]);
        }
        __syncthreads();
        int n = tid >> 2, q = tid & 3;
        int k = k0 + q * 16;
        int c = k >> 8, p = (k >> 4) & 15;
        ushort* dst = Wt + (size_t)(n0 + n) * NFLAT + p * 336 + c * 16;
        const ushort* srow = &ldsT[n][q * 16];
#pragma unroll
        for (int i = 0; i < 8; ++i) {
            ushort2 v; v.x = srow[2 * i]; v.y = srow[2 * i + 1];
            ((ushort2*)dst)[i] = v;
        }
        return;
    }

    int bp = blockIdx.x, b = bp >> 4, p = bp & 15;
    __shared__ float s[4096];
    __shared__ ushort stage[16 * 336];
    const float* src = sim + (size_t)bp * 4096;
#pragma unroll
    for (int i = 0; i < 16; ++i) s[i * 256 + tid] = src[i * 256 + tid];
    __syncthreads();

    int wo = tid & 15, ho = tid >> 4;
    float f[16], g[16];
    float sum0 = 0.f;
#pragma unroll
    for (int i = 0; i < 4; ++i)
#pragma unroll
        for (int j = 0; j < 4; ++j) {
            float e = s[(ho * 4 + i) * 64 + wo * 4 + j];
            int k2 = i * 4 + j;
            float d0 = e - 1.0f;
            sum0 += __expf(-50.f * d0 * d0);
            float d1 = e - 0.95f;
            f[k2] = __expf(-50.f * d1 * d1);
            g[k2] = __expf(-10.f * d1 - 0.5f);
        }

    stage[ho * 336 + wo] = f2bf(hist_act(sum0));
#pragma unroll
    for (int c = 1; c < 21; ++c) {
        float sv = 0.f;
#pragma unroll
        for (int k2 = 0; k2 < 16; ++k2) sv += f[k2];
        stage[ho * 336 + c * 16 + wo] = f2bf(hist_act(sv));
        if (c < 20) {
#pragma unroll
            for (int k2 = 0; k2 < 16; ++k2) { f[k2] *= g[k2]; g[k2] *= 0.36787944117f; }
        }
    }
    __syncthreads();

    const uint* ssrc = (const uint*)stage;
    char* xb = (char*)x;
#pragma unroll
    for (int it = 0; it < 11; ++it) {
        int i = it * 256 + tid;
        if (i < 2688) {
            int row = i / 168;
            int jc = i - row * 168;
            *(uint*)(xb + ((size_t)(b * 16 + row) * NFLAT + p * 336) * 2 + jc * 4) = ssrc[i];
        }
    }
}

// ---------------------------------------------------------------------------
// Kernel 2: all-register dataflow GEMM. NO LDS, NO barriers.
// grid (32 bm, 2 bn, 4 sk) x 512 thr. 8 waves = 4 wr x 2 wc.
// Wave tile: 16 rows x 64 cols (4 n-tiles). Fragments direct from global:
//   A-frag lane l: A[row0 + (l&15)][k0 + (l>>4)*8 ..+8]   (16B)
//   B-frag lane l: Bt[col0 + nt*16 + (l&15)][same k slice] (16B)
// Latency hidden by unroll-3 ILP + high occupancy (no LDS, small acc).
// ---------------------------------------------------------------------------
__global__ __launch_bounds__(512, 2) void k_gemm(const ushort* __restrict__ A,
                                                 const ushort* __restrict__ Bt,
                                                 float* __restrict__ part) {
    int bm = blockIdx.x, bn = blockIdx.y, sk = blockIdx.z;
    int tid = threadIdx.x;
    int l = tid & 63, w = tid >> 6;
    int wr = w >> 1, wc = w & 1;                 // 4 x 2
    int row0 = bm * 64 + wr * 16;
    int col0 = bn * 128 + wc * 64;
    int kbase = sk * 1344;
    int lr = l & 15, lk = l >> 4;                // frag row / k-quarter

    const ushort* gA = A  + (size_t)(row0 + lr) * NFLAT + kbase + lk * 8;
    const ushort* gB = Bt + (size_t)(col0 + lr) * NFLAT + kbase + lk * 8;

    f32x4 acc[4];
#pragma unroll
    for (int nt = 0; nt < 4; ++nt) acc[nt] = (f32x4){0.f, 0.f, 0.f, 0.f};

#pragma unroll 3
    for (int kt = 0; kt < 42; ++kt) {
        bf16x8 a = *(const bf16x8*)(gA + kt * 32);
#pragma unroll
        for (int nt = 0; nt < 4; ++nt) {
            bf16x8 b = *(const bf16x8*)(gB + (size_t)nt * 16 * NFLAT + kt * 32);
            acc[nt] = __builtin_amdgcn_mfma_f32_16x16x32_bf16(a, b, acc[nt], 0, 0, 0);
        }
    }

    // C layout: row = (lane>>4)*4 + j, col = lane&15
    float* pp = part + (size_t)sk * 2048 * 256;
    int crow = row0 + lk * 4;
#pragma unroll
    for (int nt = 0; nt < 4; ++nt) {
        int ccol = col0 + nt * 16 + lr;
#pragma unroll
        for (int j = 0; j < 4; ++j)
            pp[(size_t)(crow + j) * 256 + ccol] = acc[nt][j];
    }
}

// ---------------------------------------------------------------------------
// Kernel 3: fused split-K reduce + bias + tanh + attention + heads.
// One block per batch element, 256 threads.
// ---------------------------------------------------------------------------
__global__ __launch_bounds__(256) void k_head(
    const float* __restrict__ part,    // [4][2048][256]
    const float* __restrict__ b_flat,
    const float* __restrict__ f_add,
    const float* __restrict__ W_attn,
    const float* __restrict__ b_attn,
    const float* __restrict__ W_fadd,
    const float* __restrict__ b_fadd,
    const float* __restrict__ W_d1,
    const float* __restrict__ b_d1,
    const float* __restrict__ W_d2,
    const float* __restrict__ b_d2,
    const float* __restrict__ wfeat,
    float* __restrict__ out)           // [512]
{
    int b = blockIdx.x;
    int tid = threadIdx.x;

    __shared__ float sh1[16 * 256];
    __shared__ float slog[16];
    __shared__ float scomb[256];
    __shared__ float r0s[4], r1s[4];

#pragma unroll
    for (int i = 0; i < 16; ++i) {
        size_t row = (size_t)(b * 16 + i) * 256 + tid;
        float v = b_flat[tid];
        v += part[row] + part[524288 + row] + part[2 * 524288 + row] + part[3 * 524288 + row];
        sh1[i * 256 + tid] = fast_tanh(v);
    }
    __syncthreads();

    {
        int ho = tid >> 4, j = tid & 15;
        float sv = 0.f;
#pragma unroll
        for (int t2 = 0; t2 < 16; ++t2)
            sv += sh1[ho * 256 + j + t2 * 16] * W_attn[j + t2 * 16];
        sv += __shfl_xor(sv, 1); sv += __shfl_xor(sv, 2);
        sv += __shfl_xor(sv, 4); sv += __shfl_xor(sv, 8);
        if (j == 0) slog[ho] = sv + b_attn[0];
    }
    __syncthreads();

    float attnv[16];
    {
        float mx = -1e30f;
#pragma unroll
        for (int t2 = 0; t2 < 16; ++t2) mx = fmaxf(mx, slog[t2]);
        float sum = 0.f;
#pragma unroll
        for (int t2 = 0; t2 < 16; ++t2) { attnv[t2] = __expf(slog[t2] - mx); sum += attnv[t2]; }
        float inv = __builtin_amdgcn_rcpf(sum);
#pragma unroll
        for (int t2 = 0; t2 < 16; ++t2) attnv[t2] *= inv;
    }

    float lc = 0.f;
#pragma unroll
    for (int t2 = 0; t2 < 16; ++t2) lc += attnv[t2] * sh1[t2 * 256 + tid];
    lc = fast_tanh(lc);

    float fp = b_fadd[tid];
#pragma unroll
    for (int k = 0; k < 17; ++k) fp += f_add[b * 17 + k] * W_fadd[k * 256 + tid];
    fp = fast_tanh(fp);

    float sg = __builtin_amdgcn_rcpf(1.f + __expf(-wfeat[0]));
    scomb[tid] = (1.f - sg) * fp + sg * lc;
    __syncthreads();

    float sc = b_d1[tid];
#pragma unroll 8
    for (int k = 0; k < 256; ++k) sc += scomb[k] * W_d1[k * 256 + tid];
    sc = fast_tanh(sc);

    float p0 = sc * W_d2[tid * 2 + 0];
    float p1 = sc * W_d2[tid * 2 + 1];
#pragma unroll
    for (int off = 1; off < 64; off <<= 1) {
        p0 += __shfl_xor(p0, off);
        p1 += __shfl_xor(p1, off);
    }
    if ((tid & 63) == 0) { r0s[tid >> 6] = p0; r1s[tid >> 6] = p1; }
    __syncthreads();

    if (tid == 0) {
        float o0 = r0s[0] + r0s[1] + r0s[2] + r0s[3] + b_d2[0];
        float o1 = r1s[0] + r1s[1] + r1s[2] + r1s[3] + b_d2[1];
        float mx = fmaxf(o0, o1);
        float lse = mx + __logf(__expf(o0 - mx) + __expf(o1 - mx));
        out[b * 2 + 0] = o0 - lse;
        out[b * 2 + 1] = o1 - lse;
        out[256 + b * 2 + 0] = o0;
        out[256 + b * 2 + 1] = o1;
    }
}

// ---------------------------------------------------------------------------
extern "C" void kernel_launch(void* const* d_in, const int* in_sizes, int n_in,
                              void* d_out, int out_size, void* d_ws, size_t ws_size,
                              hipStream_t stream) {
    const float* sim    = (const float*)d_in[0];
    const float* f_add  = (const float*)d_in[1];
    const float* W_flat = (const float*)d_in[2];
    const float* b_flat = (const float*)d_in[3];
    const float* W_attn = (const float*)d_in[4];
    const float* b_attn = (const float*)d_in[5];
    const float* W_fadd = (const float*)d_in[6];
    const float* b_fadd = (const float*)d_in[7];
    const float* W_d1   = (const float*)d_in[8];
    const float* b_d1   = (const float*)d_in[9];
    const float* W_d2   = (const float*)d_in[10];
    const float* b_d2   = (const float*)d_in[11];
    const float* wfeat  = (const float*)d_in[12];
    float* out = (float*)d_out;

    ushort* x  = (ushort*)d_ws;                        // [2048][5376] bf16 (22MB)
    ushort* Wt = x + (size_t)2048 * NFLAT;             // [256][5376] bf16 (2.75MB)
    float* part = (float*)(Wt + (size_t)256 * NFLAT);  // [4][2048][256] f32 (8MB)

    hipLaunchKernelGGL(k_pre, dim3(2048 + 336), dim3(256), 0, stream, sim, x, W_flat, Wt);
    hipLaunchKernelGGL(k_gemm, dim3(32, 2, 4), dim3(512), 0, stream, x, Wt, part);
    hipLaunchKernelGGL(k_head, dim3(128), dim3(256), 0, stream,
                       part, b_flat, f_add, W_attn, b_attn, W_fadd, b_fadd,
                       W_d1, b_d1, W_d2, b_d2, wfeat, out);
}

// Round 11
// 65.919 us; speedup vs baseline: 1.4531x; 1.4531x over previous
//
#include <hip/hip_runtime.h>
#include <hip/hip_bf16.h>
#include <math.h>

#define BSZ   128
#define NP    16
#define NC    21
#define NH    256
#define HOUT  16
#define NFLAT 5376     // K (permuted layout k' = p*336 + c*16 + wo)

// fused-kernel geometry: block (bm, sk): rows 64, K-slice 672 (p = 2sk, 2sk+1)
#define XT_STRIDE 680              // ushorts per xT row (672 + 8 pad, 16B-mult, 2-way banks)
#define XT_BYTES  (64 * XT_STRIDE * 2)          // 87040
#define B_STRIDE  40               // ushorts per B row (32 + 8 pad, 16B-mult)
#define B_BUF     (256 * B_STRIDE * 2)          // 20480 B per buffer
#define LDS_TOTAL (XT_BYTES + 2 * B_BUF)        // 128000 B
#define PSTR      (2048 * 256)     // part per-sk stride (f32)

typedef __attribute__((ext_vector_type(4))) float f32x4;
typedef __attribute__((ext_vector_type(8))) short bf16x8;

__device__ __forceinline__ ushort f2bf(float v) {
    __hip_bfloat16 h = __float2bfloat16(v);
    return *reinterpret_cast<ushort*>(&h);
}

// tanh(0.01*ln(s)) via odd poly: u in [-0.23, 0.03]; err < 2e-6
__device__ __forceinline__ float hist_act(float s) {
    float u = 0.01f * __logf(fmaxf(s, 1e-10f));
    float u2 = u * u;
    return u * (1.f + u2 * (-0.33333333f + 0.13333333f * u2));
}

// tanh(x) = 1 - 2/(e^{2x}+1)
__device__ __forceinline__ float fast_tanh(float v) {
    float e = __expf(2.f * v);
    return 1.f - 2.f * __builtin_amdgcn_rcpf(e + 1.f);
}

// ---------------------------------------------------------------------------
// Kernel 0: Wt[n][k'] = bf16(W_flat[k][n]), k' = p*336 + c*16 + wo.
// 336 blocks x 256 thr (proven r6 body).
// ---------------------------------------------------------------------------
__global__ __launch_bounds__(256) void k_prep(const float* __restrict__ W,
                                              ushort* __restrict__ Wt) {
    __shared__ ushort ldsT[64][72];
    int pb = blockIdx.x;
    int kb = pb % 84, nb = pb / 84;
    int k0 = kb * 64, n0 = nb * 64;
    int tid = threadIdx.x;
    int nl = tid & 63, kq = tid >> 6;
#pragma unroll
    for (int i = 0; i < 16; ++i) {
        int kl = i * 4 + kq;
        ldsT[nl][kl] = f2bf(W[(size_t)(k0 + kl) * NH + n0 + nl]);
    }
    __syncthreads();
    int n = tid >> 2, q = tid & 3;
    int k = k0 + q * 16;
    int c = k >> 8, p = (k >> 4) & 15;
    ushort* dst = Wt + (size_t)(n0 + n) * NFLAT + p * 336 + c * 16;
    const ushort* srow = &ldsT[n][q * 16];
#pragma unroll
    for (int i = 0; i < 8; ++i) {
        ushort2 v; v.x = srow[2 * i]; v.y = srow[2 * i + 1];
        ((ushort2*)dst)[i] = v;
    }
}

// ---------------------------------------------------------------------------
// Kernel 1 (fused): RBF -> xT in LDS -> MFMA GEMM vs staged Wt.
// 256 blocks (bm = bid>>3, sk = bid&7) x 512 thr, 128 KB dynamic LDS.
// x never touches global memory.
// ---------------------------------------------------------------------------
extern "C" __global__ __launch_bounds__(512, 1) void k_fused(
    const float* __restrict__ sim,     // [128][16][64][64]
    const ushort* __restrict__ Wt,     // [256][5376] bf16
    float* __restrict__ part)          // [8][2048][256]
{
    extern __shared__ __align__(16) char smem[];
    ushort* xT = (ushort*)smem;                       // [64][XT_STRIDE]
    char* Bbase = smem + XT_BYTES;                    // 2 x B_BUF
    const int bid = blockIdx.x;
    const int bm = bid >> 3, sk = bid & 7;
    const int tid = threadIdx.x;
    const int tloc = tid >> 8, tid256 = tid & 255;

    // ================= PHASE A: RBF into LDS xT =================
    {
        float* stile = (float*)(Bbase) + tloc * 4096;   // 2 x 16KB overlay on B bufs
        int wo = tid256 & 15, ho = tid256 >> 4;

        for (int round = 0; round < 4; ++round) {
            int t8 = round * 2 + tloc;               // 0..7
            int boff = t8 >> 1, poff = t8 & 1;
            const float4* src4 = (const float4*)(sim
                + (((size_t)(4 * bm + boff)) * 16 + (2 * sk + poff)) * 4096);
            float4* s4 = (float4*)stile;
#pragma unroll
            for (int i = 0; i < 4; ++i) s4[i * 256 + tid256] = src4[i * 256 + tid256];
            __syncthreads();

            float f[16], g[16];
            float sum0 = 0.f;
#pragma unroll
            for (int i = 0; i < 4; ++i)
#pragma unroll
                for (int j = 0; j < 4; ++j) {
                    float e = stile[(ho * 4 + i) * 64 + wo * 4 + j];
                    int k2 = i * 4 + j;
                    float d0 = e - 1.0f;
                    sum0 += __expf(-50.f * d0 * d0);
                    float d1 = e - 0.95f;
                    f[k2] = __expf(-50.f * d1 * d1);
                    g[k2] = __expf(-10.f * d1 - 0.5f);
                }

            ushort* xrow = xT + (boff * 16 + ho) * XT_STRIDE + poff * 336 + wo;
            xrow[0] = f2bf(hist_act(sum0));
#pragma unroll
            for (int c = 1; c < 21; ++c) {
                float sv = 0.f;
#pragma unroll
                for (int k2 = 0; k2 < 16; ++k2) sv += f[k2];
                xrow[c * 16] = f2bf(hist_act(sv));
                if (c < 20) {
#pragma unroll
                    for (int k2 = 0; k2 < 16; ++k2) { f[k2] *= g[k2]; g[k2] *= 0.36787944117f; }
                }
            }
            __syncthreads();   // stile reuse next round; xT writes visible at end
        }
    }

    // ================= PHASE B: GEMM (21 iters of BK=32) =================
    {
        int l = tid & 63, w = tid >> 6;
        int wr = w >> 1, wc = w & 1;                // 4x2 waves; wave tile 16 x 128
        int lr = l & 15, lk = l >> 4;
        int arow = wr * 16 + lr;

        // B staging: thread t covers Wt row (t>>1), 32B half (t&1)
        int brow = tid >> 1, bhalf = tid & 1;
        const ushort* gB = Wt + (size_t)brow * NFLAT + sk * 672 + bhalf * 16;
        char* wB0 = Bbase + brow * (B_STRIDE * 2) + bhalf * 32;
        char* wB1 = wB0 + B_BUF;

        f32x4 acc[8];
#pragma unroll
        for (int nt = 0; nt < 8; ++nt) acc[nt] = (f32x4){0.f, 0.f, 0.f, 0.f};

        // prologue: load it0 (E), it1 (O) into regs
        uint4 bE0 = *(const uint4*)(gB);
        uint4 bE1 = *(const uint4*)(gB + 8);
        uint4 bO0 = *(const uint4*)(gB + 32);
        uint4 bO1 = *(const uint4*)(gB + 40);

#define COMPUTE(BUFOFF, IT)                                                      \
        {                                                                        \
            bf16x8 a = *(const bf16x8*)((const char*)xT + arow * (XT_STRIDE*2)   \
                                        + (IT) * 64 + lk * 16);                  \
            _Pragma("unroll")                                                    \
            for (int nt = 0; nt < 8; ++nt) {                                     \
                bf16x8 bb = *(const bf16x8*)(Bbase + (BUFOFF)                    \
                            + (wc * 128 + nt * 16 + lr) * (B_STRIDE*2)           \
                            + lk * 16);                                          \
                acc[nt] = __builtin_amdgcn_mfma_f32_16x16x32_bf16(a, bb, acc[nt], 0, 0, 0); \
            }                                                                    \
        }

#pragma unroll 1
        for (int m = 0; m < 10; ++m) {
            int it = 2 * m;
            __syncthreads();                       // buf0 consumers (it-2) done
            *(uint4*)(wB0) = bE0; *(uint4*)(wB0 + 16) = bE1;
            { int nit = it + 2;                    // 2m+2 <= 20 always valid
              bE0 = *(const uint4*)(gB + nit * 32);
              bE1 = *(const uint4*)(gB + nit * 32 + 8); }
            __syncthreads();                       // buf0 ready
            COMPUTE(0, it);

            __syncthreads();                       // buf1 consumers done
            *(uint4*)(wB1) = bO0; *(uint4*)(wB1 + 16) = bO1;
            if (m < 9) { int nit = it + 3;
              bO0 = *(const uint4*)(gB + nit * 32);
              bO1 = *(const uint4*)(gB + nit * 32 + 8); }
            __syncthreads();
            COMPUTE(B_BUF, it + 1);
        }
        // tail: it = 20 (held in E regs)
        __syncthreads();
        *(uint4*)(wB0) = bE0; *(uint4*)(wB0 + 16) = bE1;
        __syncthreads();
        COMPUTE(0, 20);
#undef COMPUTE

        // store partials: C row=(l>>4)*4+j, col=l&15
        float* pp = part + (size_t)sk * PSTR;
        int crow = bm * 64 + wr * 16 + lk * 4;
#pragma unroll
        for (int nt = 0; nt < 8; ++nt) {
            int ccol = wc * 128 + nt * 16 + lr;
#pragma unroll
            for (int j = 0; j < 4; ++j)
                pp[(size_t)(crow + j) * 256 + ccol] = acc[nt][j];
        }
    }
}

// ---------------------------------------------------------------------------
// Kernel 2: fused split-K reduce + bias + tanh + attention + heads.
// One block per batch element, 256 threads.
// ---------------------------------------------------------------------------
__global__ __launch_bounds__(256) void k_head(
    const float* __restrict__ part,    // [8][2048][256]
    const float* __restrict__ b_flat,
    const float* __restrict__ f_add,
    const float* __restrict__ W_attn,
    const float* __restrict__ b_attn,
    const float* __restrict__ W_fadd,
    const float* __restrict__ b_fadd,
    const float* __restrict__ W_d1,
    const float* __restrict__ b_d1,
    const float* __restrict__ W_d2,
    const float* __restrict__ b_d2,
    const float* __restrict__ wfeat,
    float* __restrict__ out)           // [512]
{
    int b = blockIdx.x;
    int tid = threadIdx.x;

    __shared__ float sh1[16 * 256];
    __shared__ float slog[16];
    __shared__ float scomb[256];
    __shared__ float r0s[4], r1s[4];

#pragma unroll
    for (int i = 0; i < 16; ++i) {
        size_t row = (size_t)(b * 16 + i) * 256 + tid;
        float v = b_flat[tid];
#pragma unroll
        for (int s = 0; s < 8; ++s) v += part[(size_t)s * PSTR + row];
        sh1[i * 256 + tid] = fast_tanh(v);
    }
    __syncthreads();

    {
        int ho = tid >> 4, j = tid & 15;
        float sv = 0.f;
#pragma unroll
        for (int t2 = 0; t2 < 16; ++t2)
            sv += sh1[ho * 256 + j + t2 * 16] * W_attn[j + t2 * 16];
        sv += __shfl_xor(sv, 1); sv += __shfl_xor(sv, 2);
        sv += __shfl_xor(sv, 4); sv += __shfl_xor(sv, 8);
        if (j == 0) slog[ho] = sv + b_attn[0];
    }
    __syncthreads();

    float attnv[16];
    {
        float mx = -1e30f;
#pragma unroll
        for (int t2 = 0; t2 < 16; ++t2) mx = fmaxf(mx, slog[t2]);
        float sum = 0.f;
#pragma unroll
        for (int t2 = 0; t2 < 16; ++t2) { attnv[t2] = __expf(slog[t2] - mx); sum += attnv[t2]; }
        float inv = __builtin_amdgcn_rcpf(sum);
#pragma unroll
        for (int t2 = 0; t2 < 16; ++t2) attnv[t2] *= inv;
    }

    float lc = 0.f;
#pragma unroll
    for (int t2 = 0; t2 < 16; ++t2) lc += attnv[t2] * sh1[t2 * 256 + tid];
    lc = fast_tanh(lc);

    float fp = b_fadd[tid];
#pragma unroll
    for (int k = 0; k < 17; ++k) fp += f_add[b * 17 + k] * W_fadd[k * 256 + tid];
    fp = fast_tanh(fp);

    float sg = __builtin_amdgcn_rcpf(1.f + __expf(-wfeat[0]));
    scomb[tid] = (1.f - sg) * fp + sg * lc;
    __syncthreads();

    float sc = b_d1[tid];
#pragma unroll 8
    for (int k = 0; k < 256; ++k) sc += scomb[k] * W_d1[k * 256 + tid];
    sc = fast_tanh(sc);

    float p0 = sc * W_d2[tid * 2 + 0];
    float p1 = sc * W_d2[tid * 2 + 1];
#pragma unroll
    for (int off = 1; off < 64; off <<= 1) {
        p0 += __shfl_xor(p0, off);
        p1 += __shfl_xor(p1, off);
    }
    if ((tid & 63) == 0) { r0s[tid >> 6] = p0; r1s[tid >> 6] = p1; }
    __syncthreads();

    if (tid == 0) {
        float o0 = r0s[0] + r0s[1] + r0s[2] + r0s[3] + b_d2[0];
        float o1 = r1s[0] + r1s[1] + r1s[2] + r1s[3] + b_d2[1];
        float mx = fmaxf(o0, o1);
        float lse = mx + __logf(__expf(o0 - mx) + __expf(o1 - mx));
        out[b * 2 + 0] = o0 - lse;
        out[b * 2 + 1] = o1 - lse;
        out[256 + b * 2 + 0] = o0;
        out[256 + b * 2 + 1] = o1;
    }
}

// ---------------------------------------------------------------------------
extern "C" void kernel_launch(void* const* d_in, const int* in_sizes, int n_in,
                              void* d_out, int out_size, void* d_ws, size_t ws_size,
                              hipStream_t stream) {
    const float* sim    = (const float*)d_in[0];
    const float* f_add  = (const float*)d_in[1];
    const float* W_flat = (const float*)d_in[2];
    const float* b_flat = (const float*)d_in[3];
    const float* W_attn = (const float*)d_in[4];
    const float* b_attn = (const float*)d_in[5];
    const float* W_fadd = (const float*)d_in[6];
    const float* b_fadd = (const float*)d_in[7];
    const float* W_d1   = (const float*)d_in[8];
    const float* b_d1   = (const float*)d_in[9];
    const float* W_d2   = (const float*)d_in[10];
    const float* b_d2   = (const float*)d_in[11];
    const float* wfeat  = (const float*)d_in[12];
    float* out = (float*)d_out;

    ushort* Wt  = (ushort*)d_ws;                        // [256][5376] bf16 (2.75MB)
    float* part = (float*)(Wt + (size_t)256 * NFLAT);   // [8][2048][256] f32 (16.8MB)

    hipLaunchKernelGGL(k_prep, dim3(336), dim3(256), 0, stream, W_flat, Wt);
    hipLaunchKernelGGL(k_fused, dim3(256), dim3(512), LDS_TOTAL, stream, sim, Wt, part);
    hipLaunchKernelGGL(k_head, dim3(128), dim3(256), 0, stream,
                       part, b_flat, f_add, W_attn, b_attn, W_fadd, b_fadd,
                       W_d1, b_d1, W_d2, b_d2, wfeat, out);
}

// Round 12
// 61.405 us; speedup vs baseline: 1.5599x; 1.0735x over previous
//
#include <hip/hip_runtime.h>
#include <hip/hip_bf16.h>
#include <math.h>

#define BSZ   128
#define NP    16
#define NC    21
#define NH    256
#define HOUT  16
#define NFLAT 5376     // K (permuted layout k' = p*336 + c*16 + wo)

// fused-kernel geometry: block (bm, sk): rows 64, K-slice 672 (p = 2sk, 2sk+1)
#define XT_STRIDE 680                      // ushorts (672 + 8 pad -> 2-way banks)
#define XT_BYTES  (64 * XT_STRIDE * 2)     // 87040
#define B_STRIDE  40                       // ushorts per B row (32 + 8 pad)
#define B_BUF     (256 * B_STRIDE * 2)     // 20480 B per buffer
#define STILE_OFF XT_BYTES                 // RBF sim tiles / GEMM B bufs overlay
#define LDS_TOTAL (XT_BYTES + 4 * 16384)   // 152576 B
#define PSTR      (2048 * 256)             // part per-sk stride (f32)

typedef __attribute__((ext_vector_type(4))) float f32x4;
typedef __attribute__((ext_vector_type(8))) short bf16x8;

__device__ __forceinline__ ushort f2bf(float v) {
    __hip_bfloat16 h = __float2bfloat16(v);
    return *reinterpret_cast<ushort*>(&h);
}

// tanh(0.01*ln(s)) via odd poly: u in [-0.23, 0.03]; err < 2e-6
__device__ __forceinline__ float hist_act(float s) {
    float u = 0.01f * __logf(fmaxf(s, 1e-10f));
    float u2 = u * u;
    return u * (1.f + u2 * (-0.33333333f + 0.13333333f * u2));
}

// tanh(x) = 1 - 2/(e^{2x}+1)
__device__ __forceinline__ float fast_tanh(float v) {
    float e = __expf(2.f * v);
    return 1.f - 2.f * __builtin_amdgcn_rcpf(e + 1.f);
}

// ---------------------------------------------------------------------------
// Kernel 0: Wt[n][k'] = bf16(W_flat[k][n]). 336 blocks x 256 thr.
// ---------------------------------------------------------------------------
__global__ __launch_bounds__(256) void k_prep(const float* __restrict__ W,
                                              ushort* __restrict__ Wt) {
    __shared__ ushort ldsT[64][72];
    int pb = blockIdx.x;
    int kb = pb % 84, nb = pb / 84;
    int k0 = kb * 64, n0 = nb * 64;
    int tid = threadIdx.x;
    int nl = tid & 63, kq = tid >> 6;
#pragma unroll
    for (int i = 0; i < 16; ++i) {
        int kl = i * 4 + kq;
        ldsT[nl][kl] = f2bf(W[(size_t)(k0 + kl) * NH + n0 + nl]);
    }
    __syncthreads();
    int n = tid >> 2, q = tid & 3;
    int k = k0 + q * 16;
    int c = k >> 8, p = (k >> 4) & 15;
    ushort* dst = Wt + (size_t)(n0 + n) * NFLAT + p * 336 + c * 16;
    const ushort* srow = &ldsT[n][q * 16];
#pragma unroll
    for (int i = 0; i < 8; ++i) {
        ushort2 v; v.x = srow[2 * i]; v.y = srow[2 * i + 1];
        ((ushort2*)dst)[i] = v;
    }
}

// ---------------------------------------------------------------------------
// Kernel 1 (fused): RBF -> xT in LDS -> MFMA GEMM vs staged Wt.
// 256 blocks (bm = bid>>3, sk = bid&7) x 1024 thr (16 waves, 4/SIMD).
// ---------------------------------------------------------------------------
extern "C" __global__ __launch_bounds__(1024, 1) void k_fused(
    const float* __restrict__ sim,     // [128][16][64][64]
    const ushort* __restrict__ Wt,     // [256][5376] bf16
    float* __restrict__ part)          // [8][2048][256]
{
    extern __shared__ __align__(16) char smem[];
    ushort* xT = (ushort*)smem;                       // [64][XT_STRIDE]
    char* Bbase = smem + STILE_OFF;                   // GEMM: 2 x B_BUF
    const int bid = blockIdx.x;
    const int bm = bid >> 3, sk = bid & 7;
    const int tid = threadIdx.x;
    const int tg = tid >> 8, tid256 = tid & 255;      // 4 groups of 256

    // ================= PHASE A: RBF into LDS xT (2 rounds x 4 tiles) =======
    {
        float* stile = (float*)(smem + STILE_OFF) + tg * 4096;
        int wo = tid256 & 15, ho = tid256 >> 4;

        for (int round = 0; round < 2; ++round) {
            int t8 = round * 4 + tg;                 // 0..7
            int boff = t8 >> 1, poff = t8 & 1;
            const float4* src4 = (const float4*)(sim
                + (((size_t)(4 * bm + boff)) * 16 + (2 * sk + poff)) * 4096);
            float4* s4 = (float4*)stile;
#pragma unroll
            for (int i = 0; i < 4; ++i) s4[i * 256 + tid256] = src4[i * 256 + tid256];
            __syncthreads();

            float f[16], g[16];
            float sum0 = 0.f;
#pragma unroll
            for (int i = 0; i < 4; ++i)
#pragma unroll
                for (int j = 0; j < 4; ++j) {
                    float e = stile[(ho * 4 + i) * 64 + wo * 4 + j];
                    int k2 = i * 4 + j;
                    float d0 = e - 1.0f;
                    sum0 += __expf(-50.f * d0 * d0);
                    float d1 = e - 0.95f;
                    f[k2] = __expf(-50.f * d1 * d1);
                    g[k2] = __expf(-10.f * d1 - 0.5f);
                }

            ushort* xrow = xT + (boff * 16 + ho) * XT_STRIDE + poff * 336 + wo;
            xrow[0] = f2bf(hist_act(sum0));
#pragma unroll
            for (int c = 1; c < 21; ++c) {
                float sv = 0.f;
#pragma unroll
                for (int k2 = 0; k2 < 16; ++k2) sv += f[k2];
                xrow[c * 16] = f2bf(hist_act(sv));
                if (c < 20) {
#pragma unroll
                    for (int k2 = 0; k2 < 16; ++k2) { f[k2] *= g[k2]; g[k2] *= 0.36787944117f; }
                }
            }
            __syncthreads();
        }
    }

    // ================= PHASE B: GEMM (21 iters of BK=32) =================
    {
        int l = tid & 63, w = tid >> 6;
        int wr = w >> 2, wc = w & 3;                // 4x4 waves; wave tile 16 x 64
        int lr = l & 15, lk = l >> 4;
        int arow = wr * 16 + lr;

        // B staging: thread t covers Wt row (t>>2), 16B quarter (t&3)
        int brow = tid >> 2, bq = tid & 3;
        const ushort* gB = Wt + (size_t)brow * NFLAT + sk * 672 + bq * 8;
        char* wB0 = Bbase + brow * (B_STRIDE * 2) + bq * 16;
        char* wB1 = wB0 + B_BUF;

        f32x4 acc[4];
#pragma unroll
        for (int nt = 0; nt < 4; ++nt) acc[nt] = (f32x4){0.f, 0.f, 0.f, 0.f};

        // prologue: load it0 (E), it1 (O) into regs
        uint4 bE = *(const uint4*)(gB);
        uint4 bO = *(const uint4*)(gB + 32);

#define COMPUTE(BUFOFF, IT)                                                      \
        {                                                                        \
            bf16x8 a = *(const bf16x8*)((const char*)xT + arow * (XT_STRIDE*2)   \
                                        + (IT) * 64 + lk * 16);                  \
            _Pragma("unroll")                                                    \
            for (int nt = 0; nt < 4; ++nt) {                                     \
                bf16x8 bb = *(const bf16x8*)(Bbase + (BUFOFF)                    \
                            + (wc * 64 + nt * 16 + lr) * (B_STRIDE*2)            \
                            + lk * 16);                                          \
                acc[nt] = __builtin_amdgcn_mfma_f32_16x16x32_bf16(a, bb, acc[nt], 0, 0, 0); \
            }                                                                    \
        }

#pragma unroll 1
        for (int m = 0; m < 10; ++m) {
            int it = 2 * m;
            __syncthreads();                       // buf0 consumers (it-2) done
            *(uint4*)(wB0) = bE;
            bE = *(const uint4*)(gB + (it + 2) * 32);
            __syncthreads();                       // buf0 ready
            COMPUTE(0, it);

            __syncthreads();                       // buf1 consumers done
            *(uint4*)(wB1) = bO;
            if (m < 9) bO = *(const uint4*)(gB + (it + 3) * 32);
            __syncthreads();
            COMPUTE(B_BUF, it + 1);
        }
        __syncthreads();
        *(uint4*)(wB0) = bE;                       // it = 20
        __syncthreads();
        COMPUTE(0, 20);
#undef COMPUTE

        // store partials: C row=(l>>4)*4+j, col=l&15
        float* pp = part + (size_t)sk * PSTR;
        int crow = bm * 64 + wr * 16 + lk * 4;
#pragma unroll
        for (int nt = 0; nt < 4; ++nt) {
            int ccol = wc * 64 + nt * 16 + lr;
#pragma unroll
            for (int j = 0; j < 4; ++j)
                pp[(size_t)(crow + j) * 256 + ccol] = acc[nt][j];
        }
    }
}

// ---------------------------------------------------------------------------
// Kernel 2: split-K reduce + bias + tanh + attention + heads.
// 128 blocks x 512 thr.
// ---------------------------------------------------------------------------
__global__ __launch_bounds__(512) void k_head(
    const float* __restrict__ part,    // [8][2048][256]
    const float* __restrict__ b_flat,
    const float* __restrict__ f_add,
    const float* __restrict__ W_attn,
    const float* __restrict__ b_attn,
    const float* __restrict__ W_fadd,
    const float* __restrict__ b_fadd,
    const float* __restrict__ W_d1,
    const float* __restrict__ b_d1,
    const float* __restrict__ W_d2,
    const float* __restrict__ b_d2,
    const float* __restrict__ wfeat,
    float* __restrict__ out)           // [512]
{
    const int b = blockIdx.x;
    const int tid = threadIdx.x;

    __shared__ float sh1[16 * 256];
    __shared__ float slog[16];
    __shared__ float scomb[256];
    __shared__ float scpart[512];
    __shared__ float r01[8];

#pragma unroll
    for (int i = 0; i < 8; ++i) {
        int idx = i * 512 + tid;
        int row = idx >> 8, col = idx & 255;
        size_t prow = (size_t)(b * 16 + row) * 256 + col;
        float v = b_flat[col];
#pragma unroll
        for (int s = 0; s < 8; ++s) v += part[(size_t)s * PSTR + prow];
        sh1[idx] = fast_tanh(v);
    }
    __syncthreads();

    if (tid < 256) {
        int ho = tid >> 4, j = tid & 15;
        float sv = 0.f;
#pragma unroll
        for (int t2 = 0; t2 < 16; ++t2)
            sv += sh1[ho * 256 + j + t2 * 16] * W_attn[j + t2 * 16];
        sv += __shfl_xor(sv, 1); sv += __shfl_xor(sv, 2);
        sv += __shfl_xor(sv, 4); sv += __shfl_xor(sv, 8);
        if (j == 0) slog[ho] = sv + b_attn[0];
    }
    __syncthreads();

    if (tid < 256) {
        float attnv[16];
        float mx = -1e30f;
#pragma unroll
        for (int t2 = 0; t2 < 16; ++t2) mx = fmaxf(mx, slog[t2]);
        float sum = 0.f;
#pragma unroll
        for (int t2 = 0; t2 < 16; ++t2) { attnv[t2] = __expf(slog[t2] - mx); sum += attnv[t2]; }
        float inv = __builtin_amdgcn_rcpf(sum);

        float lc = 0.f;
#pragma unroll
        for (int t2 = 0; t2 < 16; ++t2) lc += attnv[t2] * inv * sh1[t2 * 256 + tid];
        lc = fast_tanh(lc);

        float fp = b_fadd[tid];
#pragma unroll
        for (int k = 0; k < 17; ++k) fp += f_add[b * 17 + k] * W_fadd[k * 256 + tid];
        fp = fast_tanh(fp);

        float sg = __builtin_amdgcn_rcpf(1.f + __expf(-wfeat[0]));
        scomb[tid] = (1.f - sg) * fp + sg * lc;
    }
    __syncthreads();

    {
        int n = tid & 255, half = tid >> 8;
        float sc = 0.f;
        int k0 = half * 128;
#pragma unroll 8
        for (int k = 0; k < 128; ++k) sc += scomb[k0 + k] * W_d1[(k0 + k) * 256 + n];
        scpart[half * 256 + n] = sc;
    }
    __syncthreads();

    if (tid < 256) {
        float sc = fast_tanh(scpart[tid] + scpart[256 + tid] + b_d1[tid]);
        float p0 = sc * W_d2[tid * 2 + 0];
        float p1 = sc * W_d2[tid * 2 + 1];
#pragma unroll
        for (int off = 1; off < 64; off <<= 1) {
            p0 += __shfl_xor(p0, off);
            p1 += __shfl_xor(p1, off);
        }
        if ((tid & 63) == 0) { r01[tid >> 6] = p0; r01[4 + (tid >> 6)] = p1; }
    }
    __syncthreads();

    if (tid == 0) {
        float o0 = r01[0] + r01[1] + r01[2] + r01[3] + b_d2[0];
        float o1 = r01[4] + r01[5] + r01[6] + r01[7] + b_d2[1];
        float mx = fmaxf(o0, o1);
        float lse = mx + __logf(__expf(o0 - mx) + __expf(o1 - mx));
        out[b * 2 + 0] = o0 - lse;
        out[b * 2 + 1] = o1 - lse;
        out[256 + b * 2 + 0] = o0;
        out[256 + b * 2 + 1] = o1;
    }
}

// ---------------------------------------------------------------------------
extern "C" void kernel_launch(void* const* d_in, const int* in_sizes, int n_in,
                              void* d_out, int out_size, void* d_ws, size_t ws_size,
                              hipStream_t stream) {
    const float* sim    = (const float*)d_in[0];
    const float* f_add  = (const float*)d_in[1];
    const float* W_flat = (const float*)d_in[2];
    const float* b_flat = (const float*)d_in[3];
    const float* W_attn = (const float*)d_in[4];
    const float* b_attn = (const float*)d_in[5];
    const float* W_fadd = (const float*)d_in[6];
    const float* b_fadd = (const float*)d_in[7];
    const float* W_d1   = (const float*)d_in[8];
    const float* b_d1   = (const float*)d_in[9];
    const float* W_d2   = (const float*)d_in[10];
    const float* b_d2   = (const float*)d_in[11];
    const float* wfeat  = (const float*)d_in[12];
    float* out = (float*)d_out;

    ushort* Wt  = (ushort*)d_ws;                        // [256][5376] bf16 (2.75MB)
    float* part = (float*)(Wt + (size_t)256 * NFLAT);   // [8][2048][256] f32 (16.8MB)

    hipLaunchKernelGGL(k_prep, dim3(336), dim3(256), 0, stream, W_flat, Wt);
    hipLaunchKernelGGL(k_fused, dim3(256), dim3(1024), LDS_TOTAL, stream, sim, Wt, part);
    hipLaunchKernelGGL(k_head, dim3(128), dim3(512), 0, stream,
                       part, b_flat, f_add, W_attn, b_attn, W_fadd, b_fadd,
                       W_d1, b_d1, W_d2, b_d2, wfeat, out);
}